// Round 7
// baseline (300.061 us; speedup 1.0000x reference)
//
#include <hip/hip_runtime.h>

// LSTM: B=4096, T=512, INPUT=1, HIDDEN=32, OUTPUT=1 (fp32)
//
// Round-7 restructure: across rounds 1-6 the compiler NEVER kept 128 weight
// floats/lane register-resident (VGPR stuck at 84-104; remat-reload or
// scratch-spill instead), regardless of launch_bounds / waves_per_eu /
// opaque-asm. So reduce the requirement: ONE batch per 64-lane wave, lane
// (j, hi) owns only TWO gate rows:
//   hi=0: rows i_j (row j)      and g_j (row 64+j)
//   hi=1: rows f_j (row 32+j)   and o_j (row 96+j)
// => 64 weight floats/lane, total pressure ~95 VGPR — inside the envelope
// the compiler demonstrably tolerates.
//
// Per step: both halves compute their 2 dots; activation type (sigmoid vs
// tanh) is selected branchlessly via per-lane constants folded into the
// exp2 argument and a final fma; one __shfl_xor(.,32) pair swaps (i,g) with
// (f,o) so BOTH lanes of a pair compute identical c_j and h_j (bitwise same
// -> duplicate LDS write of h is benign). No fences, no barriers: same-wave
// DS ops are in-order (validated rounds 5/6, absmax 0).
//
// Weights stay RAW (activation scale applied to the exp2 input, +2 mul/step)
// so a remat cannot re-execute scale-muls; OPAQUE pins the loaded values.
// Grid = 4096 single-wave blocks = 4 waves/SIMD, pinned by waves_per_eu(4,4)
// (VGPR budget 128).

#define HID 32
#define TSTEPS 512
#define BLOCK 64
#define L2E 1.44269504088896340736f

#define OPAQUE(v) asm("" : "+v"(v))

__device__ __forceinline__ float rcp_fast(float x) {
    return __builtin_amdgcn_rcpf(x);            // v_rcp_f32
}
__device__ __forceinline__ float exp2_fast(float x) {
    return __builtin_amdgcn_exp2f(x);           // v_exp_f32
}

__global__ __launch_bounds__(BLOCK)
__attribute__((amdgpu_waves_per_eu(4, 4)))
void lstm_fused_kernel(const float* __restrict__ x,
                       const float* __restrict__ W_ih,
                       const float* __restrict__ W_hh,
                       const float* __restrict__ b_ih,
                       const float* __restrict__ b_hh,
                       const float* __restrict__ W_fc,
                       const float* __restrict__ b_fc,
                       float* __restrict__ out)
{
    __shared__ __align__(16) float x_s[TSTEPS];   // 2 KiB
    __shared__ __align__(16) float h_s[HID];      // 128 B

    const int tid = threadIdx.x;
    const int j   = tid & 31;        // hidden unit
    const int hi  = tid >> 5;        // 0: (i,g) rows, 1: (f,o) rows
    const int b   = blockIdx.x;      // one batch element per wave

    // ---- stage x: 512 floats = 64 lanes x 2 float4 (coalesced) ----
    {
        const float4* xsrc = reinterpret_cast<const float4*>(x + (size_t)b * TSTEPS);
        float4* xdst = reinterpret_cast<float4*>(x_s);
        xdst[tid]      = xsrc[tid];
        xdst[tid + 64] = xsrc[tid + 64];
    }

    // ---- this lane's two gate rows (RAW weights, no pre-scaling) ----
    const int rowA = hi * HID + j;            // i_j or f_j  (both sigmoid)
    const int rowB = 2 * HID + hi * HID + j;  // g_j (tanh) or o_j (sigmoid)

    float wA[HID], wB[HID];
    {
        const float4* rA = reinterpret_cast<const float4*>(W_hh + (size_t)rowA * HID);
        const float4* rB = reinterpret_cast<const float4*>(W_hh + (size_t)rowB * HID);
        #pragma unroll
        for (int k = 0; k < HID / 4; ++k) {
            float4 v;
            v = rA[k]; wA[4*k]=v.x; wA[4*k+1]=v.y; wA[4*k+2]=v.z; wA[4*k+3]=v.w;
            v = rB[k]; wB[4*k]=v.x; wB[4*k+1]=v.y; wB[4*k+2]=v.z; wB[4*k+3]=v.w;
        }
        #pragma unroll
        for (int m = 0; m < HID; ++m) { OPAQUE(wA[m]); OPAQUE(wB[m]); }
    }
    const float wihA = W_ih[rowA];
    const float wihB = W_ih[rowB];
    const float bsA  = b_ih[rowA] + b_hh[rowA];
    const float bsB  = b_ih[rowB] + b_hh[rowB];

    // activation selectors (lane-constant => cndmask-free in the loop)
    const float sA = -L2E;                          // sigmoid exp2 scale
    const float sB = hi ? -L2E : -2.0f * L2E;       // o: sigmoid, g: tanh
    const float mB = hi ? 1.0f : 2.0f;
    const float aB = hi ? 0.0f : -1.0f;

    // ---- init ----
    h_s[j] = 0.0f;          // both halves write identical 0
    float c = 0.0f, hcur = 0.0f;

    // ---- recurrence: zero fences/barriers (same-wave in-order DS) ----
    #pragma unroll 1
    for (int t = 0; t < TSTEPS; ++t) {
        const float xv = x_s[t];

        float GA = fmaf(xv, wihA, bsA);
        float GB = fmaf(xv, wihB, bsB);

        const float4* hr = reinterpret_cast<const float4*>(h_s);
        #pragma unroll
        for (int k = 0; k < HID / 4; ++k) {
            float4 hv = hr[k];        // same addr all lanes -> broadcast
            GA = fmaf(hv.x, wA[4*k  ], GA);
            GB = fmaf(hv.x, wB[4*k  ], GB);
            GA = fmaf(hv.y, wA[4*k+1], GA);
            GB = fmaf(hv.y, wB[4*k+1], GB);
            GA = fmaf(hv.z, wA[4*k+2], GA);
            GB = fmaf(hv.z, wB[4*k+2], GB);
            GA = fmaf(hv.w, wA[4*k+3], GA);
            GB = fmaf(hv.w, wB[4*k+3], GB);
        }

        // activations: actA = sigmoid(GA); resB = tanh(GB) or sigmoid(GB)
        const float actA = rcp_fast(1.0f + exp2_fast(GA * sA));
        const float rB_  = rcp_fast(1.0f + exp2_fast(GB * sB));
        const float resB = fmaf(mB, rB_, aB);

        // swap halves: (i,g) <-> (f,o)
        const float s1 = __shfl_xor(actA, 32);
        const float s2 = __shfl_xor(resB, 32);
        const float ii = hi ? s1   : actA;
        const float ff = hi ? actA : s1;
        const float gg = hi ? s2   : resB;
        const float oo = hi ? resB : s2;

        // both lanes of the pair compute identical c_j, h_j
        c = fmaf(ff, c, ii * gg);
        const float rC = rcp_fast(1.0f + exp2_fast(c * (-2.0f * L2E)));
        const float tc = fmaf(2.0f, rC, -1.0f);     // tanh(c)
        hcur = oo * tc;

        h_s[j] = hcur;      // duplicate write, identical value: benign
    }

    // ---- final FC: out[b] = dot(h_T, W_fc) + b_fc ----
    float p = hcur * W_fc[j];
    #pragma unroll
    for (int off = 16; off >= 1; off >>= 1)
        p += __shfl_xor(p, off);    // reduces within each 32-half
    if (tid == 0)
        out[b] = p + b_fc[0];
}

extern "C" void kernel_launch(void* const* d_in, const int* in_sizes, int n_in,
                              void* d_out, int out_size, void* d_ws, size_t ws_size,
                              hipStream_t stream) {
    const float* x    = (const float*)d_in[0];
    const float* W_ih = (const float*)d_in[1];
    const float* W_hh = (const float*)d_in[2];
    const float* b_ih = (const float*)d_in[3];
    const float* b_hh = (const float*)d_in[4];
    const float* W_fc = (const float*)d_in[5];
    const float* b_fc = (const float*)d_in[6];
    float* out = (float*)d_out;

    const int B = in_sizes[0] / TSTEPS;   // 4096 (INPUT=1)
    lstm_fused_kernel<<<B, BLOCK, 0, stream>>>(x, W_ih, W_hh, b_ih, b_hh,
                                               W_fc, b_fc, out);
}

// Round 8
// 281.711 us; speedup vs baseline: 1.0651x; 1.0651x over previous
//
#include <hip/hip_runtime.h>

// LSTM: B=4096, T=512, INPUT=1, HIDDEN=32, OUTPUT=1 (fp32)
// One 64-lane wave per block, 2 batch elements (one per 32-lane half).
// Lane j owns hidden unit j: 4 recurrent weight rows (128 fp32) in VGPRs.
//
// Round-8 single-variable experiment on top of round 6 (which is correct,
// absmax 0, but slow): rounds 1-7 all show the compiler sinking/remat-ing
// the weight loads into the timestep loop instead of keeping 128 floats
// live (VGPR_Count 60-104 < weight footprint every round). The weight
// values were always *rematerializable load chains*, so the scheduler's
// pressure heuristic prefers re-executing them. Fix: pin each weight with
//   asm volatile("" : "=v"(w) : "0"(w))
// a VOLATILE asm def with a matching constraint: zero instructions, but
// the result is non-rematerializable / non-duplicable / non-sinkable, so
// the only legal choices are VGPR-resident or an (absurd) per-iteration
// scratch spill. Budget: waves_per_eu(2,2) => 256 VGPRs; demand ~190.
//
// Everything else is identical to round 6: no fences, no barriers in the
// loop (same-wave DS ops execute in order; the h_s store->load may-alias
// dependence keeps program order), log2(e) folded into W/b so activations
// are rcp(1+exp2(-a)).

#define HID 32
#define TSTEPS 512
#define BPW 2            // batch elements per wave/block
#define BLOCK 64
#define L2E 1.44269504088896340736f

// volatile + matching constraint: value must materialize in a VGPR and
// stay allocator-visible; producer cannot be remat'd into the loop.
#define PIN(v) asm volatile("" : "=v"(v) : "0"(v))

__device__ __forceinline__ float rcp_fast(float x) {
    return __builtin_amdgcn_rcpf(x);            // v_rcp_f32
}
__device__ __forceinline__ float exp2_fast(float x) {
    return __builtin_amdgcn_exp2f(x);           // v_exp_f32
}
// a pre-scaled by log2(e): sigmoid(a/L2E)
__device__ __forceinline__ float sigmoid_l2(float a) {
    return rcp_fast(1.0f + exp2_fast(-a));
}
// a pre-scaled by 2*log2(e): tanh(a/(2*L2E))
__device__ __forceinline__ float tanh_l2(float a) {
    return fmaf(2.0f, rcp_fast(1.0f + exp2_fast(-a)), -1.0f);
}

__global__ __launch_bounds__(BLOCK)
__attribute__((amdgpu_waves_per_eu(2, 2)))
void lstm_fused_kernel(const float* __restrict__ x,
                       const float* __restrict__ W_ih,
                       const float* __restrict__ W_hh,
                       const float* __restrict__ b_ih,
                       const float* __restrict__ b_hh,
                       const float* __restrict__ W_fc,
                       const float* __restrict__ b_fc,
                       float* __restrict__ out)
{
    __shared__ __align__(16) float x_s[BPW * TSTEPS];   // 4 KiB
    __shared__ __align__(16) float h_s[BPW][HID];       // 256 B

    const int tid = threadIdx.x;
    const int lb  = tid >> 5;        // local batch 0..1 (half-wave)
    const int j   = tid & 31;        // hidden unit
    const int b0  = blockIdx.x * BPW;

    // ---- stage x (coalesced float4). Same wave produces and consumes:
    // same-wave DS ops are in-order, no barrier needed (block = 1 wave). ----
    {
        const float4* xsrc = reinterpret_cast<const float4*>(x + (size_t)b0 * TSTEPS);
        float4* xdst = reinterpret_cast<float4*>(x_s);
        #pragma unroll
        for (int k = 0; k < (BPW * TSTEPS) / (4 * BLOCK); ++k)
            xdst[tid + k * BLOCK] = xsrc[tid + k * BLOCK];
    }

    // ---- per-unit weights into registers, pre-scaled, PINNED ----
    // gate 0=i, 1=f, 2=g, 3=o ; scale L2E for i/f/o, 2*L2E for g
    float w0[HID], w1[HID], w2[HID], w3[HID];
    {
        const float4* r0 = reinterpret_cast<const float4*>(W_hh + (size_t)(0 * HID + j) * HID);
        const float4* r1 = reinterpret_cast<const float4*>(W_hh + (size_t)(1 * HID + j) * HID);
        const float4* r2 = reinterpret_cast<const float4*>(W_hh + (size_t)(2 * HID + j) * HID);
        const float4* r3 = reinterpret_cast<const float4*>(W_hh + (size_t)(3 * HID + j) * HID);
        #pragma unroll
        for (int k = 0; k < HID / 4; ++k) {
            float4 v;
            v = r0[k]; w0[4*k]=v.x*L2E;      w0[4*k+1]=v.y*L2E;      w0[4*k+2]=v.z*L2E;      w0[4*k+3]=v.w*L2E;
            v = r1[k]; w1[4*k]=v.x*L2E;      w1[4*k+1]=v.y*L2E;      w1[4*k+2]=v.z*L2E;      w1[4*k+3]=v.w*L2E;
            v = r2[k]; w2[4*k]=v.x*2.0f*L2E; w2[4*k+1]=v.y*2.0f*L2E; w2[4*k+2]=v.z*2.0f*L2E; w2[4*k+3]=v.w*2.0f*L2E;
            v = r3[k]; w3[4*k]=v.x*L2E;      w3[4*k+1]=v.y*L2E;      w3[4*k+2]=v.z*L2E;      w3[4*k+3]=v.w*L2E;
        }
        #pragma unroll
        for (int m = 0; m < HID; ++m) {
            PIN(w0[m]); PIN(w1[m]); PIN(w2[m]); PIN(w3[m]);
        }
    }
    float wih0 = W_ih[j]         * L2E;
    float wih1 = W_ih[HID + j]   * L2E;
    float wih2 = W_ih[2*HID + j] * 2.0f * L2E;
    float wih3 = W_ih[3*HID + j] * L2E;
    float bs0  = (b_ih[j]         + b_hh[j])         * L2E;
    float bs1  = (b_ih[HID + j]   + b_hh[HID + j])   * L2E;
    float bs2  = (b_ih[2*HID + j] + b_hh[2*HID + j]) * 2.0f * L2E;
    float bs3  = (b_ih[3*HID + j] + b_hh[3*HID + j]) * L2E;
    PIN(wih0); PIN(wih1); PIN(wih2); PIN(wih3);
    PIN(bs0);  PIN(bs1);  PIN(bs2);  PIN(bs3);

    // ---- init state (same-wave in-order DS: no fence needed) ----
    h_s[lb][j] = 0.0f;
    float c = 0.0f, hcur = 0.0f;

    // ---- recurrence: ZERO fences/barriers. Ordering comes from the
    // may-alias dependence store(h_s) -> next-iter loads(h_s). ----
    #pragma unroll 1
    for (int t = 0; t < TSTEPS; ++t) {
        const float xv = x_s[lb * TSTEPS + t];

        float a0 = fmaf(xv, wih0, bs0);
        float a1 = fmaf(xv, wih1, bs1);
        float a2 = fmaf(xv, wih2, bs2);
        float a3 = fmaf(xv, wih3, bs3);

        const float4* hr = reinterpret_cast<const float4*>(&h_s[lb][0]);
        #pragma unroll
        for (int k = 0; k < HID / 4; ++k) {
            float4 hv = hr[k];
            a0 = fmaf(hv.x, w0[4*k  ], a0);
            a1 = fmaf(hv.x, w1[4*k  ], a1);
            a2 = fmaf(hv.x, w2[4*k  ], a2);
            a3 = fmaf(hv.x, w3[4*k  ], a3);
            a0 = fmaf(hv.y, w0[4*k+1], a0);
            a1 = fmaf(hv.y, w1[4*k+1], a1);
            a2 = fmaf(hv.y, w2[4*k+1], a2);
            a3 = fmaf(hv.y, w3[4*k+1], a3);
            a0 = fmaf(hv.z, w0[4*k+2], a0);
            a1 = fmaf(hv.z, w1[4*k+2], a1);
            a2 = fmaf(hv.z, w2[4*k+2], a2);
            a3 = fmaf(hv.z, w3[4*k+2], a3);
            a0 = fmaf(hv.w, w0[4*k+3], a0);
            a1 = fmaf(hv.w, w1[4*k+3], a1);
            a2 = fmaf(hv.w, w2[4*k+3], a2);
            a3 = fmaf(hv.w, w3[4*k+3], a3);
        }

        const float ig = sigmoid_l2(a0);
        const float fg = sigmoid_l2(a1);
        const float gg = tanh_l2(a2);
        const float og = sigmoid_l2(a3);
        c    = fmaf(fg, c, ig * gg);
        hcur = og * tanh_l2((2.0f * L2E) * c);

        h_s[lb][j] = hcur;
    }

    // ---- final FC: out[b] = dot(h_T, W_fc) + b_fc ----
    float p = hcur * W_fc[j];
    #pragma unroll
    for (int off = 16; off >= 1; off >>= 1)
        p += __shfl_xor(p, off);   // xor masks <=16 stay within each half
    if (j == 0)
        out[b0 + lb] = p + b_fc[0];
}

extern "C" void kernel_launch(void* const* d_in, const int* in_sizes, int n_in,
                              void* d_out, int out_size, void* d_ws, size_t ws_size,
                              hipStream_t stream) {
    const float* x    = (const float*)d_in[0];
    const float* W_ih = (const float*)d_in[1];
    const float* W_hh = (const float*)d_in[2];
    const float* b_ih = (const float*)d_in[3];
    const float* b_hh = (const float*)d_in[4];
    const float* W_fc = (const float*)d_in[5];
    const float* b_fc = (const float*)d_in[6];
    float* out = (float*)d_out;

    const int B = in_sizes[0] / TSTEPS;   // 4096 (INPUT=1)
    const int grid = B / BPW;             // 2048 blocks, 1 wave each
    lstm_fused_kernel<<<grid, BLOCK, 0, stream>>>(x, W_ih, W_hh, b_ih, b_hh,
                                                  W_fc, b_fc, out);
}

// Round 10
// 277.592 us; speedup vs baseline: 1.0809x; 1.0148x over previous
//
#include <hip/hip_runtime.h>
#include <stdint.h>

// LSTM: B=4096, T=512, INPUT=1, HIDDEN=32, OUTPUT=1 (fp32)
// One 64-lane wave per block, 2 batch elements (one per 32-lane half).
// Lane j owns hidden unit j: 4 recurrent weight rows (128 fp32) parked in
// physical VGPRs by a single inline-asm recurrence loop (rounds 1-8 proved
// the HIP register allocator will never keep them resident on its own).
//
// Round-10 fixes vs round 9 (which produced impossible >1e5 outputs --
// bounded-math argument shows the LOOP couldn't have; a compiler-side
// register got trashed, prime suspect the hand-picked s80/scc clobbers):
//   * loop counter in v210, branch via v_cmp_gt_u32 vcc + s_cbranch_vccnz
//     -- zero SGPR/scc interaction
//   * only row-i base pointer passed (2x u32); rows f/g/o derived in-asm
//     (+4096 B steps) -- 6 fewer live-in VGPR operands
//   * no asm output: h_T is read back from LDS h_s[lb][j] by C code after
//     the asm ("memory" clobber + in-asm lgkmcnt(0) order it)
//
// Register map (all clobbered):
//   v32-v63   h[0..31]         (8x ds_read_b128 broadcast)
//   v64-v95   W_hh row j    (i)    v96-v127  row 32+j (f)
//   v128-v159 W_hh row 64+j (g)    v160-v191 row 96+j (o)
//   v192-v195 gate accs | v196 xv | v197-v204 act temps | v205 c | v206 h
//   v207 x cursor | v208:209 weight addr pair | v210 counter
// h exchange: per-half LDS row, no barriers (same-wave DS ops are in-order;
// validated rounds 5-8, absmax 0). LDS offsets = low 32 bits of generic ptr.

#define HID 32
#define TSTEPS 512
#define BPW 2
#define BLOCK 64

#define FMA4(h,wi,wf,wg,wo) \
  "v_fmac_f32 v192, v" h ", v" wi "\n\t" \
  "v_fmac_f32 v193, v" h ", v" wf "\n\t" \
  "v_fmac_f32 v194, v" h ", v" wg "\n\t" \
  "v_fmac_f32 v195, v" h ", v" wo "\n\t"

__global__ __launch_bounds__(BLOCK)
__attribute__((amdgpu_waves_per_eu(2, 2)))
void lstm_fused_kernel(const float* __restrict__ x,
                       const float* __restrict__ W_ih,
                       const float* __restrict__ W_hh,
                       const float* __restrict__ b_ih,
                       const float* __restrict__ b_hh,
                       const float* __restrict__ W_fc,
                       const float* __restrict__ b_fc,
                       float* __restrict__ out)
{
    __shared__ __align__(16) float x_s[BPW * TSTEPS];   // 4 KiB
    __shared__ __align__(16) float h_s[BPW][HID];       // 256 B

    const int tid = threadIdx.x;
    const int lb  = tid >> 5;        // local batch 0..1 (half-wave)
    const int j   = tid & 31;        // hidden unit
    const int b0  = blockIdx.x * BPW;

    // ---- stage x (coalesced float4); same-wave in-order DS means the asm's
    // reads observe these writes; "memory" clobber orders them. ----
    {
        const float4* xsrc = reinterpret_cast<const float4*>(x + (size_t)b0 * TSTEPS);
        float4* xdst = reinterpret_cast<float4*>(x_s);
        #pragma unroll
        for (int k = 0; k < (BPW * TSTEPS) / (4 * BLOCK); ++k)
            xdst[tid + k * BLOCK] = xsrc[tid + k * BLOCK];
    }

    // row-i base address for this lane, split into 32-bit halves
    const uint64_t wa = (uint64_t)(uintptr_t)(W_hh + (size_t)j * HID);
    const uint32_t wlo = (uint32_t)wa;
    const uint32_t whi = (uint32_t)(wa >> 32);

    // raw scalar params
    const float wih0 = W_ih[j];
    const float wih1 = W_ih[HID + j];
    const float wih2 = W_ih[2 * HID + j];
    const float wih3 = W_ih[3 * HID + j];
    const float bs0  = b_ih[j]           + b_hh[j];
    const float bs1  = b_ih[HID + j]     + b_hh[HID + j];
    const float bs2  = b_ih[2 * HID + j] + b_hh[2 * HID + j];
    const float bs3  = b_ih[3 * HID + j] + b_hh[3 * HID + j];

    // LDS byte offsets (low 32 bits of generic pointer = LDS offset)
    const uint32_t xb = (uint32_t)(uintptr_t)(&x_s[0]) + (uint32_t)(lb * TSTEPS * 4);
    const uint32_t hr = (uint32_t)(uintptr_t)(&h_s[0][0]) + (uint32_t)(lb * HID * 4);
    const uint32_t hw = hr + (uint32_t)(j * 4);

    asm volatile(
        // ======== prologue: park 128 weights in v64-v191 ========
        "v_mov_b32 v208, %[wlo]\n\t"
        "v_mov_b32 v209, %[whi]\n\t"
        "global_load_dwordx4 v[64:67],   v[208:209], off\n\t"
        "global_load_dwordx4 v[68:71],   v[208:209], off offset:16\n\t"
        "global_load_dwordx4 v[72:75],   v[208:209], off offset:32\n\t"
        "global_load_dwordx4 v[76:79],   v[208:209], off offset:48\n\t"
        "global_load_dwordx4 v[80:83],   v[208:209], off offset:64\n\t"
        "global_load_dwordx4 v[84:87],   v[208:209], off offset:80\n\t"
        "global_load_dwordx4 v[88:91],   v[208:209], off offset:96\n\t"
        "global_load_dwordx4 v[92:95],   v[208:209], off offset:112\n\t"
        "v_add_co_u32 v208, vcc, 0x1000, v208\n\t"
        "v_addc_co_u32 v209, vcc, 0, v209, vcc\n\t"
        "global_load_dwordx4 v[96:99],   v[208:209], off\n\t"
        "global_load_dwordx4 v[100:103], v[208:209], off offset:16\n\t"
        "global_load_dwordx4 v[104:107], v[208:209], off offset:32\n\t"
        "global_load_dwordx4 v[108:111], v[208:209], off offset:48\n\t"
        "global_load_dwordx4 v[112:115], v[208:209], off offset:64\n\t"
        "global_load_dwordx4 v[116:119], v[208:209], off offset:80\n\t"
        "global_load_dwordx4 v[120:123], v[208:209], off offset:96\n\t"
        "global_load_dwordx4 v[124:127], v[208:209], off offset:112\n\t"
        "v_add_co_u32 v208, vcc, 0x1000, v208\n\t"
        "v_addc_co_u32 v209, vcc, 0, v209, vcc\n\t"
        "global_load_dwordx4 v[128:131], v[208:209], off\n\t"
        "global_load_dwordx4 v[132:135], v[208:209], off offset:16\n\t"
        "global_load_dwordx4 v[136:139], v[208:209], off offset:32\n\t"
        "global_load_dwordx4 v[140:143], v[208:209], off offset:48\n\t"
        "global_load_dwordx4 v[144:147], v[208:209], off offset:64\n\t"
        "global_load_dwordx4 v[148:151], v[208:209], off offset:80\n\t"
        "global_load_dwordx4 v[152:155], v[208:209], off offset:96\n\t"
        "global_load_dwordx4 v[156:159], v[208:209], off offset:112\n\t"
        "v_add_co_u32 v208, vcc, 0x1000, v208\n\t"
        "v_addc_co_u32 v209, vcc, 0, v209, vcc\n\t"
        "global_load_dwordx4 v[160:163], v[208:209], off\n\t"
        "global_load_dwordx4 v[164:167], v[208:209], off offset:16\n\t"
        "global_load_dwordx4 v[168:171], v[208:209], off offset:32\n\t"
        "global_load_dwordx4 v[172:175], v[208:209], off offset:48\n\t"
        "global_load_dwordx4 v[176:179], v[208:209], off offset:64\n\t"
        "global_load_dwordx4 v[180:183], v[208:209], off offset:80\n\t"
        "global_load_dwordx4 v[184:187], v[208:209], off offset:96\n\t"
        "global_load_dwordx4 v[188:191], v[208:209], off offset:112\n\t"
        "v_mov_b32 v205, 0\n\t"                 // c = 0
        "v_mov_b32 v206, 0\n\t"                 // h = 0
        "ds_write_b32 %[hw], v206\n\t"          // h_s init
        "v_mov_b32 v207, %[xb]\n\t"             // x cursor
        "v_mov_b32 v210, 0\n\t"                 // t = 0
        "s_waitcnt vmcnt(0)\n\t"
        // ======== timestep loop ========
        "LSTM_T_%=:\n\t"
        "ds_read_b32 v196, v207\n\t"            // xv
        "ds_read_b128 v[32:35], %[hr]\n\t"      // h (broadcast reads)
        "ds_read_b128 v[36:39], %[hr] offset:16\n\t"
        "ds_read_b128 v[40:43], %[hr] offset:32\n\t"
        "ds_read_b128 v[44:47], %[hr] offset:48\n\t"
        "ds_read_b128 v[48:51], %[hr] offset:64\n\t"
        "ds_read_b128 v[52:55], %[hr] offset:80\n\t"
        "ds_read_b128 v[56:59], %[hr] offset:96\n\t"
        "ds_read_b128 v[60:63], %[hr] offset:112\n\t"
        "v_add_u32 v207, 4, v207\n\t"
        "s_waitcnt lgkmcnt(8)\n\t"              // oldest (xv) retired
        "v_fma_f32 v192, v196, %[wi0], %[q0]\n\t"
        "v_fma_f32 v193, v196, %[wi1], %[q1]\n\t"
        "v_fma_f32 v194, v196, %[wi2], %[q2]\n\t"
        "v_fma_f32 v195, v196, %[wi3], %[q3]\n\t"
        "s_waitcnt lgkmcnt(0)\n\t"              // all h ready
        FMA4("32","64","96","128","160")
        FMA4("33","65","97","129","161")
        FMA4("34","66","98","130","162")
        FMA4("35","67","99","131","163")
        FMA4("36","68","100","132","164")
        FMA4("37","69","101","133","165")
        FMA4("38","70","102","134","166")
        FMA4("39","71","103","135","167")
        FMA4("40","72","104","136","168")
        FMA4("41","73","105","137","169")
        FMA4("42","74","106","138","170")
        FMA4("43","75","107","139","171")
        FMA4("44","76","108","140","172")
        FMA4("45","77","109","141","173")
        FMA4("46","78","110","142","174")
        FMA4("47","79","111","143","175")
        FMA4("48","80","112","144","176")
        FMA4("49","81","113","145","177")
        FMA4("50","82","114","146","178")
        FMA4("51","83","115","147","179")
        FMA4("52","84","116","148","180")
        FMA4("53","85","117","149","181")
        FMA4("54","86","118","150","182")
        FMA4("55","87","119","151","183")
        FMA4("56","88","120","152","184")
        FMA4("57","89","121","153","185")
        FMA4("58","90","122","154","186")
        FMA4("59","91","123","155","187")
        FMA4("60","92","124","156","188")
        FMA4("61","93","125","157","189")
        FMA4("62","94","126","158","190")
        FMA4("63","95","127","159","191")
        // activations: sigmoid = rcp(1+exp2(-L2E*a)); tanh = 2*rcp(1+exp2(-2L2E*a))-1
        "v_mul_f32 v197, 0xbfb8aa3b, v192\n\t"
        "v_mul_f32 v198, 0xbfb8aa3b, v193\n\t"
        "v_mul_f32 v199, 0xc038aa3b, v194\n\t"
        "v_mul_f32 v200, 0xbfb8aa3b, v195\n\t"
        "v_exp_f32 v197, v197\n\t"
        "v_exp_f32 v198, v198\n\t"
        "v_exp_f32 v199, v199\n\t"
        "v_exp_f32 v200, v200\n\t"
        "v_add_f32 v197, 1.0, v197\n\t"
        "v_add_f32 v198, 1.0, v198\n\t"
        "v_add_f32 v199, 1.0, v199\n\t"
        "v_add_f32 v200, 1.0, v200\n\t"
        "v_rcp_f32 v197, v197\n\t"              // ig
        "v_rcp_f32 v198, v198\n\t"              // fg
        "v_rcp_f32 v199, v199\n\t"
        "v_rcp_f32 v200, v200\n\t"              // og
        "v_fma_f32 v201, 2.0, v199, -1.0\n\t"   // gg
        "v_mul_f32 v202, v197, v201\n\t"        // ig*gg
        "v_fma_f32 v205, v198, v205, v202\n\t"  // c = fg*c + ig*gg
        "v_mul_f32 v203, 0xc038aa3b, v205\n\t"
        "v_exp_f32 v203, v203\n\t"
        "v_add_u32 v210, 1, v210\n\t"           // t++ (spaces exp->add)
        "v_add_f32 v203, 1.0, v203\n\t"
        "v_rcp_f32 v203, v203\n\t"
        "v_cmp_gt_u32 vcc, 512, v210\n\t"       // (spaces rcp->fma)
        "v_fma_f32 v204, 2.0, v203, -1.0\n\t"   // tanh(c)
        "v_mul_f32 v206, v200, v204\n\t"        // h = og*tanh(c)
        "ds_write_b32 %[hw], v206\n\t"
        "s_cbranch_vccnz LSTM_T_%=\n\t"
        // ======== epilogue: drain so C-side h_s read is valid ========
        "s_waitcnt vmcnt(0) lgkmcnt(0)\n\t"
        :
        : [wlo] "v"(wlo), [whi] "v"(whi),
          [xb] "v"(xb), [hr] "v"(hr), [hw] "v"(hw),
          [wi0] "v"(wih0), [wi1] "v"(wih1), [wi2] "v"(wih2), [wi3] "v"(wih3),
          [q0] "v"(bs0), [q1] "v"(bs1), [q2] "v"(bs2), [q3] "v"(bs3)
        : "memory", "vcc",
          "v32","v33","v34","v35","v36","v37","v38","v39",
          "v40","v41","v42","v43","v44","v45","v46","v47",
          "v48","v49","v50","v51","v52","v53","v54","v55",
          "v56","v57","v58","v59","v60","v61","v62","v63",
          "v64","v65","v66","v67","v68","v69","v70","v71",
          "v72","v73","v74","v75","v76","v77","v78","v79",
          "v80","v81","v82","v83","v84","v85","v86","v87",
          "v88","v89","v90","v91","v92","v93","v94","v95",
          "v96","v97","v98","v99","v100","v101","v102","v103",
          "v104","v105","v106","v107","v108","v109","v110","v111",
          "v112","v113","v114","v115","v116","v117","v118","v119",
          "v120","v121","v122","v123","v124","v125","v126","v127",
          "v128","v129","v130","v131","v132","v133","v134","v135",
          "v136","v137","v138","v139","v140","v141","v142","v143",
          "v144","v145","v146","v147","v148","v149","v150","v151",
          "v152","v153","v154","v155","v156","v157","v158","v159",
          "v160","v161","v162","v163","v164","v165","v166","v167",
          "v168","v169","v170","v171","v172","v173","v174","v175",
          "v176","v177","v178","v179","v180","v181","v182","v183",
          "v184","v185","v186","v187","v188","v189","v190","v191",
          "v192","v193","v194","v195","v196","v197","v198","v199",
          "v200","v201","v202","v203","v204","v205","v206","v207",
          "v208","v209","v210");

    // h_T for this (batch, unit) is in LDS — read back in C
    const float hcur = h_s[lb][j];

    // ---- final FC: out[b] = dot(h_T, W_fc) + b_fc ----
    float p = hcur * W_fc[j];
    #pragma unroll
    for (int off = 16; off >= 1; off >>= 1)
        p += __shfl_xor(p, off);   // xor masks <=16 stay within each half
    if (j == 0)
        out[b0 + lb] = p + b_fc[0];
}

extern "C" void kernel_launch(void* const* d_in, const int* in_sizes, int n_in,
                              void* d_out, int out_size, void* d_ws, size_t ws_size,
                              hipStream_t stream) {
    const float* x    = (const float*)d_in[0];
    const float* W_ih = (const float*)d_in[1];
    const float* W_hh = (const float*)d_in[2];
    const float* b_ih = (const float*)d_in[3];
    const float* b_hh = (const float*)d_in[4];
    const float* W_fc = (const float*)d_in[5];
    const float* b_fc = (const float*)d_in[6];
    float* out = (float*)d_out;

    const int B = in_sizes[0] / TSTEPS;   // 4096 (INPUT=1)
    const int grid = B / BPW;             // 2048 blocks, 1 wave each
    lstm_fused_kernel<<<grid, BLOCK, 0, stream>>>(x, W_ih, W_hh, b_ih, b_hh,
                                                  W_fc, b_fc, out);
}